// Round 1
// baseline (3168.001 us; speedup 1.0000x reference)
//
#include <hip/hip_runtime.h>
#include <math.h>

// Problem constants
#define BB    4
#define SS    2048
#define DM    2048
#define NE    8
#define HDIM  256
#define NOPE_ 128
#define Q3    768      // 3*HD
#define NG    32       // NE*BB groups
#define SCALE_ 0.0625f // 1/sqrt(256)

// ws byte offsets
#define WSO_COUNTS 0        // 32 int
#define WSO_ML     128      // 1 int
#define WSO_P      192      // 32 int
#define WSO_SEL    512      // BB*SS int (32KB)
#define WSO_SEQ    40960    // NG*SS int (256KB)
#define WSO_QKV    (1<<20)  // f32 [NG][ml][768], runtime ml stride

// ---------------- K1: gating logits + top2 selection ----------------
__global__ __launch_bounds__(64) void k_gate(const float* __restrict__ X,
                                             const float* __restrict__ wg,
                                             const float* __restrict__ bg,
                                             int* __restrict__ sel,
                                             int* __restrict__ counts) {
    int row = blockIdx.x;            // b*SS + s
    int lane = threadIdx.x;          // 64
    const float* xr = X + (size_t)row * DM;
    float acc[NE];
#pragma unroll
    for (int e = 0; e < NE; ++e) acc[e] = 0.f;
    for (int d = lane; d < DM; d += 64) {
        float x = xr[d];
        const float* w = wg + (size_t)d * NE;
#pragma unroll
        for (int e = 0; e < NE; ++e) acc[e] += x * w[e];
    }
#pragma unroll
    for (int e = 0; e < NE; ++e) {
#pragma unroll
        for (int off = 32; off; off >>= 1) acc[e] += __shfl_xor(acc[e], off);
    }
    if (lane == 0) {
        float lg[NE];
#pragma unroll
        for (int e = 0; e < NE; ++e) lg[e] = acc[e] + bg[e];
        int e1 = 0; float v1 = lg[0];
        for (int e = 1; e < NE; ++e) if (lg[e] > v1) { v1 = lg[e]; e1 = e; }
        int e2 = -1; float v2 = -3.4e38f;
        for (int e = 0; e < NE; ++e) { if (e == e1) continue; if (lg[e] > v2) { v2 = lg[e]; e2 = e; } }
        int b = row / SS;
        sel[row] = (1 << e1) | (1 << e2);
        atomicAdd(&counts[e1 * BB + b], 1);
        atomicAdd(&counts[e2 * BB + b], 1);
    }
}

// ---------------- K2: max_len + padding counts ----------------
__global__ __launch_bounds__(64) void k_maxlen(const int* __restrict__ counts,
                                               int* __restrict__ mlp, int* __restrict__ P) {
    __shared__ int red[64];
    int t = threadIdx.x;
    int c = (t < NG) ? counts[t] : 0;
    red[t] = c; __syncthreads();
    for (int off = 32; off; off >>= 1) { if (t < off) red[t] = max(red[t], red[t + off]); __syncthreads(); }
    int ml = red[0];
    if (t == 0) *mlp = ml;
    if (t < NG) P[t] = ml - c;
}

// ---------------- K3: build seq_ids (selected + lowest-index pads, ascending) ----------------
__device__ __forceinline__ int scan256(int v, int tid, int* tmp, int& total) {
    tmp[tid] = v; __syncthreads();
#pragma unroll
    for (int off = 1; off < 256; off <<= 1) {
        int t = (tid >= off) ? tmp[tid - off] : 0;
        __syncthreads();
        tmp[tid] += t;
        __syncthreads();
    }
    total = tmp[255];
    int incl = tmp[tid];
    __syncthreads();
    return incl - v;
}

__global__ __launch_bounds__(256) void k_seq(const int* __restrict__ sel,
                                             const int* __restrict__ P,
                                             int* __restrict__ seq) {
    __shared__ int tmp[256];
    __shared__ int bases[2];   // running unsel rank, running take rank
    int g = blockIdx.x; int e = g >> 2, b = g & 3;
    int p = P[g];
    int tid = threadIdx.x;
    if (tid == 0) { bases[0] = 0; bases[1] = 0; }
    __syncthreads();
    for (int c = 0; c < SS; c += 256) {
        int s = c + tid;
        int sb = (sel[b * SS + s] >> e) & 1;
        int un = 1 - sb;
        int tot;
        int exc = scan256(un, tid, tmp, tot);
        int rank_un = bases[0] + exc;
        int take = sb | (un & ((rank_un < p) ? 1 : 0));
        int tot2;
        int exc2 = scan256(take, tid, tmp, tot2);
        int pos = bases[1] + exc2;
        if (take) seq[g * SS + pos] = s;
        __syncthreads();
        if (tid == 0) { bases[0] += tot; bases[1] += tot2; }
        __syncthreads();
    }
}

// ---------------- K4: QKV GEMM per group: [ml x 2048] @ [2048 x 768] ----------------
__global__ __launch_bounds__(256) void k_qkv(const float* __restrict__ X,
                                             const float* __restrict__ Wqkv,
                                             const float* __restrict__ bqkv,
                                             const int* __restrict__ mlp,
                                             const int* __restrict__ seq,
                                             float* __restrict__ qkv) {
    int ml = *mlp;
    int g = blockIdx.z; int e = g >> 2, b = g & 3;
    int k0 = blockIdx.y * 32; if (k0 >= ml) return;
    int c0 = blockIdx.x * 64;
    int tid = threadIdx.x;
    int tc = tid & 31;        // cols: c0+tc, c0+tc+32
    int tr = tid >> 5;        // rows: tr*4 .. tr*4+3
    __shared__ float xs[32][36];   // 16B-aligned rows (144B)
    __shared__ float wsT[64][33];  // [col][d], conflict-free stride
    __shared__ int sids[32];
    int rows = min(32, ml - k0);
    if (tid < 32) sids[tid] = (tid < rows) ? seq[g * SS + k0 + tid] : 0;
    __syncthreads();
    float acc[4][2];
#pragma unroll
    for (int r = 0; r < 4; ++r) { acc[r][0] = 0.f; acc[r][1] = 0.f; }

    for (int dt = 0; dt < DM; dt += 32) {
        // stage X tile: 32 rows x 32 d (float4)
        {
            int r = tid >> 3, q = tid & 7;
            float4 v = make_float4(0.f, 0.f, 0.f, 0.f);
            if (r < rows) v = *(const float4*)&X[((size_t)b * SS + sids[r]) * DM + dt + q * 4];
            *(float4*)&xs[r][q * 4] = v;
        }
        // stage W tile transposed: 32 d x 64 c  ->  wsT[c][d]
        for (int i = tid; i < 32 * 64; i += 256) {
            int d = i >> 6, c = i & 63;
            wsT[c][d] = Wqkv[((size_t)e * DM + dt + d) * Q3 + c0 + c];
        }
        __syncthreads();
#pragma unroll
        for (int d = 0; d < 32; ++d) {
            float w0 = wsT[tc][d];
            float w1 = wsT[tc + 32][d];
#pragma unroll
            for (int r = 0; r < 4; ++r) {
                float x = xs[tr * 4 + r][d];
                acc[r][0] = fmaf(x, w0, acc[r][0]);
                acc[r][1] = fmaf(x, w1, acc[r][1]);
            }
        }
        __syncthreads();
    }
    float b0 = bqkv[e * Q3 + c0 + tc];
    float b1 = bqkv[e * Q3 + c0 + tc + 32];
#pragma unroll
    for (int r = 0; r < 4; ++r) {
        int k = tr * 4 + r;
        if (k < rows) {
            float* rowp = qkv + ((size_t)g * ml + k0 + k) * Q3 + c0;
            rowp[tc]      = acc[r][0] + b0;
            rowp[tc + 32] = acc[r][1] + b1;
        }
    }
}

// ---------------- K4b: RoPE in-place on q[128:256] and k[384:512] ----------------
__global__ __launch_bounds__(128) void k_rope(const int* __restrict__ mlp,
                                              float* __restrict__ qkv) {
    int ml = *mlp;
    int k = blockIdx.x; if (k >= ml) return;
    int g = blockIdx.y; int e = g >> 2;
    int j = threadIdx.x;           // 0..127 : 64 q-pairs then 64 k-pairs
    int jp = j & 63;
    float* row = qkv + ((size_t)g * ml + k) * Q3;
    int off = (j < 64) ? (NOPE_ + 2 * jp) : (HDIM + NOPE_ + 2 * jp);
    // freqs[i] = 1/10000^(i/512), i = e*64+jp  (exponent exact in f32)
    float xexp = (float)(e * 64 + jp) * (1.0f / 512.0f);
    float freq = 1.0f / powf(10000.0f, xexp);
    float ang = (float)k * freq;
    float c = cosf(ang), s = sinf(ang);
    float a = row[off], bb = row[off + 1];
    row[off]     = a * c - bb * s;
    row[off + 1] = a * s + bb * c;
}

// ---------------- K5: attention (online softmax), ctx written into q slot ----------------
__global__ __launch_bounds__(256) void k_attn(const int* __restrict__ mlp,
                                              const int* __restrict__ seq,
                                              const float* __restrict__ mask,
                                              float* __restrict__ qkv) {
    int ml = *mlp;
    int g = blockIdx.y; int b = g & 3;
    int q0 = blockIdx.x * 16;
    if (q0 >= ml) return;
    int nq = min(16, ml - q0);
    __shared__ float qs[16][260];
    __shared__ float ks[16][260];
    __shared__ float vs[16][260];
    __shared__ float lt[16][17];
    __shared__ float mrow[16], srow[16], frow[16];
    __shared__ int sj[16];
    int tid = threadIdx.x;
    float ctx[16];
#pragma unroll
    for (int r = 0; r < 16; ++r) ctx[r] = 0.f;
    if (tid < 16) { mrow[tid] = -1e30f; srow[tid] = 0.f; }
    // load q tile (float4)
    for (int i = tid; i < 16 * 64; i += 256) {
        int r = i >> 6, q4 = i & 63;
        float4 v = make_float4(0.f, 0.f, 0.f, 0.f);
        if (r < nq) v = *(const float4*)&qkv[((size_t)g * ml + q0 + r) * Q3 + q4 * 4];
        *(float4*)&qs[r][q4 * 4] = v;
    }
    __syncthreads();
    int rr = tid >> 4, jj = tid & 15;
    for (int j0 = 0; j0 < ml; j0 += 16) {
        int nj = min(16, ml - j0);
        for (int i = tid; i < 16 * 64; i += 256) {
            int r = i >> 6, q4 = i & 63;
            float4 kv = make_float4(0.f, 0.f, 0.f, 0.f);
            float4 vv = make_float4(0.f, 0.f, 0.f, 0.f);
            if (r < nj) {
                const float* rp = qkv + ((size_t)g * ml + j0 + r) * Q3;
                kv = *(const float4*)&rp[HDIM + q4 * 4];
                vv = *(const float4*)&rp[2 * HDIM + q4 * 4];
            }
            *(float4*)&ks[r][q4 * 4] = kv;
            *(float4*)&vs[r][q4 * 4] = vv;
        }
        if (tid < 16) sj[tid] = (tid < nj) ? seq[g * SS + j0 + tid] : 0;
        __syncthreads();
        // logits: thread (rr,jj)
        float dot = 0.f;
#pragma unroll 8
        for (int d = 0; d < HDIM; ++d) dot = fmaf(qs[rr][d], ks[jj][d], dot);
        float lg;
        if (jj < nj) {
            float m = mask[b * SS + sj[jj]];
            lg = dot * SCALE_ - 1e6f * (1.f - m);
        } else lg = -1e30f;
        lt[rr][jj] = lg;
        __syncthreads();
        if (tid < 16) {
            int r = tid;
            float tmax = lt[r][0];
#pragma unroll
            for (int j = 1; j < 16; ++j) tmax = fmaxf(tmax, lt[r][j]);
            float newm = fmaxf(mrow[r], tmax);
            float f = expf(mrow[r] - newm);
            float ssum = 0.f;
#pragma unroll
            for (int j = 0; j < 16; ++j) { float pv = expf(lt[r][j] - newm); lt[r][j] = pv; ssum += pv; }
            srow[r] = srow[r] * f + ssum;
            mrow[r] = newm; frow[r] = f;
        }
        __syncthreads();
#pragma unroll
        for (int r = 0; r < 16; ++r) {
            float a = ctx[r] * frow[r];
#pragma unroll
            for (int j = 0; j < 16; ++j) a = fmaf(lt[r][j], vs[j][tid], a);
            ctx[r] = a;
        }
        __syncthreads();
    }
    // write ctx into q slot (cols 0..255)
    for (int r = 0; r < nq; ++r) {
        qkv[((size_t)g * ml + q0 + r) * Q3 + tid] = ctx[r] / srow[r];
    }
}

// ---------------- K6: out-projection [ml x 256] @ [256 x 2048] + atomic scatter ----------------
__global__ __launch_bounds__(256) void k_out(const int* __restrict__ mlp,
                                             const int* __restrict__ seq,
                                             const float* __restrict__ Wff,
                                             const float* __restrict__ bff,
                                             const float* __restrict__ qkv,
                                             float* __restrict__ out) {
    int ml = *mlp;
    int g = blockIdx.z; int e = g >> 2, b = g & 3;
    int k0 = blockIdx.y * 32; if (k0 >= ml) return;
    int c0 = blockIdx.x * 256;
    int tid = threadIdx.x;
    __shared__ float cs[32][260];
    int rows = min(32, ml - k0);
    for (int i = tid; i < 32 * 64; i += 256) {
        int r = i >> 6, q4 = i & 63;
        float4 v = make_float4(0.f, 0.f, 0.f, 0.f);
        if (r < rows) v = *(const float4*)&qkv[((size_t)g * ml + k0 + r) * Q3 + q4 * 4];
        *(float4*)&cs[r][q4 * 4] = v;
    }
    __syncthreads();
    float acc[32];
#pragma unroll
    for (int r = 0; r < 32; ++r) acc[r] = 0.f;
    const float* wp = Wff + (size_t)e * HDIM * DM + c0 + tid;
    for (int d4 = 0; d4 < 64; ++d4) {
        float w0 = wp[(size_t)(4 * d4 + 0) * DM];
        float w1 = wp[(size_t)(4 * d4 + 1) * DM];
        float w2 = wp[(size_t)(4 * d4 + 2) * DM];
        float w3 = wp[(size_t)(4 * d4 + 3) * DM];
#pragma unroll
        for (int r = 0; r < 32; ++r) {
            float4 cv = *(const float4*)&cs[r][d4 * 4];
            acc[r] = fmaf(cv.x, w0, fmaf(cv.y, w1, fmaf(cv.z, w2, fmaf(cv.w, w3, acc[r]))));
        }
    }
    float bias = bff[c0 + tid];
    for (int r = 0; r < rows; ++r) {
        int sid = seq[g * SS + k0 + r];
        atomicAdd(&out[((size_t)b * SS + sid) * DM + c0 + tid], acc[r] + bias);
    }
}

// ---------------- launch ----------------
extern "C" void kernel_launch(void* const* d_in, const int* in_sizes, int n_in,
                              void* d_out, int out_size, void* d_ws, size_t ws_size,
                              hipStream_t stream) {
    const float* X    = (const float*)d_in[0];
    const float* mask = (const float*)d_in[1];
    const float* wg   = (const float*)d_in[2];
    const float* bg   = (const float*)d_in[3];
    const float* Wqkv = (const float*)d_in[4];
    const float* bqkv = (const float*)d_in[5];
    const float* Wff  = (const float*)d_in[6];
    const float* bff  = (const float*)d_in[7];
    float* out = (float*)d_out;
    char* ws = (char*)d_ws;
    int* counts = (int*)(ws + WSO_COUNTS);
    int* mlp    = (int*)(ws + WSO_ML);
    int* P      = (int*)(ws + WSO_P);
    int* sel    = (int*)(ws + WSO_SEL);
    int* seq    = (int*)(ws + WSO_SEQ);
    float* qkv  = (float*)(ws + WSO_QKV);

    hipMemsetAsync(ws, 0, 512, stream);
    hipMemsetAsync(d_out, 0, (size_t)out_size * sizeof(float), stream);

    k_gate<<<BB * SS, 64, 0, stream>>>(X, wg, bg, sel, counts);
    k_maxlen<<<1, 64, 0, stream>>>(counts, mlp, P);
    k_seq<<<NG, 256, 0, stream>>>(sel, P, seq);
    k_qkv<<<dim3(12, 64, NG), 256, 0, stream>>>(X, Wqkv, bqkv, mlp, seq, qkv);
    k_rope<<<dim3(SS, NG), 128, 0, stream>>>(mlp, qkv);
    k_attn<<<dim3(128, NG), 256, 0, stream>>>(mlp, seq, mask, qkv);
    k_out<<<dim3(8, 64, NG), 256, 0, stream>>>(mlp, seq, Wff, bff, qkv, out);
}

// Round 2
// 1531.114 us; speedup vs baseline: 2.0691x; 2.0691x over previous
//
#include <hip/hip_runtime.h>
#include <math.h>

// Problem constants
#define BB    4
#define SS    2048
#define DM    2048
#define NE    8
#define HDIM  256
#define NOPE_ 128
#define Q3    768
#define NG    32
#define SCALE_ 0.0625f

typedef __attribute__((ext_vector_type(8))) short short8;
typedef __attribute__((ext_vector_type(8))) __bf16 bf16x8;
typedef __attribute__((ext_vector_type(4))) float floatx4;

// ws byte offsets
#define WSO_COUNTS 0
#define WSO_ML     128
#define WSO_P      192
#define WSO_SEL    512
#define WSO_SEQ    40960
#define WSO_XB     0x100000ull    // Xb bf16: 32 MB
#define WSO_WQT    0x2200000ull   // WqkvT bf16 [e][768][2048]: 24 MB
#define WSO_WFT    0x3A00000ull   // WffT bf16 [e][2048][256]: 8 MB
#define WSO_QKV    0x4200000ull   // qkv bf16 [g][ml][768], runtime ml

__device__ __forceinline__ float bf2f(ushort u) {
    union { unsigned i; float f; } v; v.i = ((unsigned)u) << 16; return v.f;
}
__device__ __forceinline__ ushort f2bf(float f) {
    union { float f; unsigned i; } v; v.f = f;
    unsigned u = v.i;
    return (ushort)((u + 0x7FFFu + ((u >> 16) & 1u)) >> 16);
}

// ---------------- K1: gating logits + top2 selection (unchanged, exact f32) ----------------
__global__ __launch_bounds__(64) void k_gate(const float* __restrict__ X,
                                             const float* __restrict__ wg,
                                             const float* __restrict__ bg,
                                             int* __restrict__ sel,
                                             int* __restrict__ counts) {
    int row = blockIdx.x;
    int lane = threadIdx.x;
    const float* xr = X + (size_t)row * DM;
    float acc[NE];
#pragma unroll
    for (int e = 0; e < NE; ++e) acc[e] = 0.f;
    for (int d = lane; d < DM; d += 64) {
        float x = xr[d];
        const float* w = wg + (size_t)d * NE;
#pragma unroll
        for (int e = 0; e < NE; ++e) acc[e] += x * w[e];
    }
#pragma unroll
    for (int e = 0; e < NE; ++e) {
#pragma unroll
        for (int off = 32; off; off >>= 1) acc[e] += __shfl_xor(acc[e], off);
    }
    if (lane == 0) {
        float lg[NE];
#pragma unroll
        for (int e = 0; e < NE; ++e) lg[e] = acc[e] + bg[e];
        int e1 = 0; float v1 = lg[0];
        for (int e = 1; e < NE; ++e) if (lg[e] > v1) { v1 = lg[e]; e1 = e; }
        int e2 = -1; float v2 = -3.4e38f;
        for (int e = 0; e < NE; ++e) { if (e == e1) continue; if (lg[e] > v2) { v2 = lg[e]; e2 = e; } }
        int b = row / SS;
        sel[row] = (1 << e1) | (1 << e2);
        atomicAdd(&counts[e1 * BB + b], 1);
        atomicAdd(&counts[e2 * BB + b], 1);
    }
}

// ---------------- K2: max_len + padding counts ----------------
__global__ __launch_bounds__(64) void k_maxlen(const int* __restrict__ counts,
                                               int* __restrict__ mlp, int* __restrict__ P) {
    __shared__ int red[64];
    int t = threadIdx.x;
    int c = (t < NG) ? counts[t] : 0;
    red[t] = c; __syncthreads();
    for (int off = 32; off; off >>= 1) { if (t < off) red[t] = max(red[t], red[t + off]); __syncthreads(); }
    int ml = red[0];
    if (t == 0) *mlp = ml;
    if (t < NG) P[t] = ml - c;
}

// ---------------- K3: build seq_ids ----------------
__device__ __forceinline__ int scan256(int v, int tid, int* tmp, int& total) {
    tmp[tid] = v; __syncthreads();
#pragma unroll
    for (int off = 1; off < 256; off <<= 1) {
        int t = (tid >= off) ? tmp[tid - off] : 0;
        __syncthreads();
        tmp[tid] += t;
        __syncthreads();
    }
    total = tmp[255];
    int incl = tmp[tid];
    __syncthreads();
    return incl - v;
}

__global__ __launch_bounds__(256) void k_seq(const int* __restrict__ sel,
                                             const int* __restrict__ P,
                                             int* __restrict__ seq) {
    __shared__ int tmp[256];
    __shared__ int bases[2];
    int g = blockIdx.x; int e = g >> 2, b = g & 3;
    int p = P[g];
    int tid = threadIdx.x;
    if (tid == 0) { bases[0] = 0; bases[1] = 0; }
    __syncthreads();
    for (int c = 0; c < SS; c += 256) {
        int s = c + tid;
        int sb = (sel[b * SS + s] >> e) & 1;
        int un = 1 - sb;
        int tot;
        int exc = scan256(un, tid, tmp, tot);
        int rank_un = bases[0] + exc;
        int take = sb | (un & ((rank_un < p) ? 1 : 0));
        int tot2;
        int exc2 = scan256(take, tid, tmp, tot2);
        int pos = bases[1] + exc2;
        if (take) seq[g * SS + pos] = s;
        __syncthreads();
        if (tid == 0) { bases[0] += tot; bases[1] += tot2; }
        __syncthreads();
    }
}

// ---------------- prep: X -> bf16 ----------------
__global__ __launch_bounds__(256) void k_cvtX(const float* __restrict__ X, ushort* __restrict__ Xb) {
    size_t i = ((size_t)blockIdx.x * 256 + threadIdx.x) * 8;
    float4 f0 = *(const float4*)&X[i];
    float4 f1 = *(const float4*)&X[i + 4];
    short8 o;
    o[0] = (short)f2bf(f0.x); o[1] = (short)f2bf(f0.y); o[2] = (short)f2bf(f0.z); o[3] = (short)f2bf(f0.w);
    o[4] = (short)f2bf(f1.x); o[5] = (short)f2bf(f1.y); o[6] = (short)f2bf(f1.z); o[7] = (short)f2bf(f1.w);
    *(short8*)&Xb[i] = o;
}

// ---------------- prep: W [e][K][N] f32 -> Wt [e][N][K] bf16 ----------------
__global__ __launch_bounds__(256) void k_cvtWT(const float* __restrict__ src, ushort* __restrict__ dst,
                                               int K, int N) {
    __shared__ float tile[64][65];
    int e = blockIdx.z;
    int n0 = blockIdx.x * 64, k0 = blockIdx.y * 64;
    int tid = threadIdx.x;
    for (int i = tid; i < 4096; i += 256) {
        int rr = i >> 6, cc = i & 63;
        tile[rr][cc] = src[((size_t)e * K + k0 + rr) * N + n0 + cc];
    }
    __syncthreads();
    for (int i = tid; i < 4096; i += 256) {
        int rr = i >> 6, cc = i & 63;
        dst[((size_t)e * N + n0 + rr) * K + k0 + cc] = f2bf(tile[cc][rr]);
    }
}

// ---------------- K4: QKV GEMM, bf16 MFMA 128x128xBK64 ----------------
__global__ __launch_bounds__(256) void k_qkv_mfma(const ushort* __restrict__ Xb,
                                                  const ushort* __restrict__ WqT,
                                                  const float* __restrict__ bqkv,
                                                  const int* __restrict__ mlp,
                                                  const int* __restrict__ seq,
                                                  ushort* __restrict__ qkvb) {
    int ml = *mlp;
    int g = blockIdx.z, e = g >> 2, b = g & 3;
    int k0 = blockIdx.y * 128; if (k0 >= ml) return;
    int c0 = blockIdx.x * 128;
    int tid = threadIdx.x;
    __shared__ short As[128 * 64];   // [row][64k] bf16, XOR-swizzled 16B chunks
    __shared__ short Bs[128 * 64];   // [col][64k] bf16 (WqkvT rows), same swizzle

    int r = tid >> 1, half = tid & 1;
    int gr = k0 + r;
    int sid = (gr < ml) ? seq[g * SS + gr] : 0;
    const ushort* aSrc = Xb + ((size_t)b * SS + sid) * DM + half * 32;
    const ushort* bSrc = WqT + ((size_t)(e * Q3 + c0 + r)) * DM + half * 32;
    char* aw = (char*)As + (size_t)r * 128;
    char* bw = (char*)Bs + (size_t)r * 128;
    int wbase = half * 64;
    int xo = (r & 7) << 4;

    int w = tid >> 6, l = tid & 63;
    int wr = w >> 1, wc = w & 1, lr = l & 15, kb = l >> 4;
    floatx4 acc[4][4] = {};

    int aoff[4][2], boff[4][2];
#pragma unroll
    for (int m = 0; m < 4; ++m) {
        int row = wr * 64 + m * 16 + lr;
#pragma unroll
        for (int s = 0; s < 2; ++s) aoff[m][s] = (row * 128 + s * 64 + kb * 16) ^ ((row & 7) << 4);
    }
#pragma unroll
    for (int n = 0; n < 4; ++n) {
        int row = wc * 64 + n * 16 + lr;
#pragma unroll
        for (int s = 0; s < 2; ++s) boff[n][s] = (row * 128 + s * 64 + kb * 16) ^ ((row & 7) << 4);
    }

    for (int dt = 0; dt < DM; dt += 64) {
#pragma unroll
        for (int i = 0; i < 4; ++i) {
            short8 va = *(const short8*)(aSrc + dt + i * 8);
            short8 vb = *(const short8*)(bSrc + dt + i * 8);
            *(short8*)(aw + ((wbase + i * 16) ^ xo)) = va;
            *(short8*)(bw + ((wbase + i * 16) ^ xo)) = vb;
        }
        __syncthreads();
        bf16x8 af[4][2], bfv[4][2];
#pragma unroll
        for (int m = 0; m < 4; ++m) {
            af[m][0] = *(const bf16x8*)((char*)As + aoff[m][0]);
            af[m][1] = *(const bf16x8*)((char*)As + aoff[m][1]);
        }
#pragma unroll
        for (int n = 0; n < 4; ++n) {
            bfv[n][0] = *(const bf16x8*)((char*)Bs + boff[n][0]);
            bfv[n][1] = *(const bf16x8*)((char*)Bs + boff[n][1]);
        }
#pragma unroll
        for (int m = 0; m < 4; ++m)
#pragma unroll
            for (int n = 0; n < 4; ++n) {
                acc[m][n] = __builtin_amdgcn_mfma_f32_16x16x32_bf16(af[m][0], bfv[n][0], acc[m][n], 0, 0, 0);
                acc[m][n] = __builtin_amdgcn_mfma_f32_16x16x32_bf16(af[m][1], bfv[n][1], acc[m][n], 0, 0, 0);
            }
        __syncthreads();
    }
    // epilogue: +bias, store bf16
#pragma unroll
    for (int n = 0; n < 4; ++n) {
        int col = c0 + wc * 64 + n * 16 + lr;
        float bias = bqkv[e * Q3 + col];
#pragma unroll
        for (int m = 0; m < 4; ++m) {
            int rb = k0 + wr * 64 + m * 16 + kb * 4;
#pragma unroll
            for (int j = 0; j < 4; ++j) {
                int grow = rb + j;
                if (grow < ml) qkvb[((size_t)g * ml + grow) * Q3 + col] = f2bf(acc[m][n][j] + bias);
            }
        }
    }
}

// ---------------- K4b: RoPE in-place (bf16) ----------------
__global__ __launch_bounds__(128) void k_rope(const int* __restrict__ mlp,
                                              ushort* __restrict__ qkvb) {
    int ml = *mlp;
    int k = blockIdx.x; if (k >= ml) return;
    int g = blockIdx.y; int e = g >> 2;
    int j = threadIdx.x;
    int jp = j & 63;
    ushort* row = qkvb + ((size_t)g * ml + k) * Q3;
    int off = (j < 64) ? (NOPE_ + 2 * jp) : (HDIM + NOPE_ + 2 * jp);
    float xexp = (float)(e * 64 + jp) * (1.0f / 512.0f);
    float freq = 1.0f / powf(10000.0f, xexp);
    float ang = (float)k * freq;
    float c = cosf(ang), s = sinf(ang);
    float a = bf2f(row[off]), bb = bf2f(row[off + 1]);
    row[off]     = f2bf(a * c - bb * s);
    row[off + 1] = f2bf(a * s + bb * c);
}

// ---------------- K5: attention (fp32 online softmax, bf16 I/O) ----------------
__global__ __launch_bounds__(256) void k_attn(const int* __restrict__ mlp,
                                              const int* __restrict__ seq,
                                              const float* __restrict__ mask,
                                              ushort* __restrict__ qkvb) {
    int ml = *mlp;
    int g = blockIdx.y; int b = g & 3;
    int q0 = blockIdx.x * 16;
    if (q0 >= ml) return;
    int nq = min(16, ml - q0);
    __shared__ float qs[16][260];
    __shared__ float ks[16][260];
    __shared__ float vs[16][260];
    __shared__ float lt[16][17];
    __shared__ float mrow[16], srow[16], frow[16];
    __shared__ int sj[16];
    int tid = threadIdx.x;
    float ctx[16];
#pragma unroll
    for (int r = 0; r < 16; ++r) ctx[r] = 0.f;
    if (tid < 16) { mrow[tid] = -1e30f; srow[tid] = 0.f; }
    // load q tile (bf16 -> f32)
    for (int i = tid; i < 512; i += 256) {
        int r = i >> 5, ch = i & 31;
        if (r < nq) {
            short8 v = *(const short8*)&qkvb[((size_t)g * ml + q0 + r) * Q3 + ch * 8];
#pragma unroll
            for (int u = 0; u < 8; ++u) qs[r][ch * 8 + u] = bf2f((ushort)v[u]);
        } else {
#pragma unroll
            for (int u = 0; u < 8; ++u) qs[r][ch * 8 + u] = 0.f;
        }
    }
    __syncthreads();
    int rr = tid >> 4, jj = tid & 15;
    for (int j0 = 0; j0 < ml; j0 += 16) {
        int nj = min(16, ml - j0);
        for (int i = tid; i < 512; i += 256) {
            int r = i >> 5, ch = i & 31;
            if (r < nj) {
                const ushort* rp = qkvb + ((size_t)g * ml + j0 + r) * Q3;
                short8 kv = *(const short8*)&rp[HDIM + ch * 8];
                short8 vv = *(const short8*)&rp[2 * HDIM + ch * 8];
#pragma unroll
                for (int u = 0; u < 8; ++u) {
                    ks[r][ch * 8 + u] = bf2f((ushort)kv[u]);
                    vs[r][ch * 8 + u] = bf2f((ushort)vv[u]);
                }
            } else {
#pragma unroll
                for (int u = 0; u < 8; ++u) { ks[r][ch * 8 + u] = 0.f; vs[r][ch * 8 + u] = 0.f; }
            }
        }
        if (tid < 16) sj[tid] = (tid < nj) ? seq[g * SS + j0 + tid] : 0;
        __syncthreads();
        float dot = 0.f;
#pragma unroll 8
        for (int d = 0; d < HDIM; ++d) dot = fmaf(qs[rr][d], ks[jj][d], dot);
        float lg;
        if (jj < nj) {
            float m = mask[b * SS + sj[jj]];
            lg = dot * SCALE_ - 1e6f * (1.f - m);
        } else lg = -1e30f;
        lt[rr][jj] = lg;
        __syncthreads();
        if (tid < 16) {
            int r = tid;
            float tmax = lt[r][0];
#pragma unroll
            for (int j = 1; j < 16; ++j) tmax = fmaxf(tmax, lt[r][j]);
            float newm = fmaxf(mrow[r], tmax);
            float f = expf(mrow[r] - newm);
            float ssum = 0.f;
#pragma unroll
            for (int j = 0; j < 16; ++j) { float pv = expf(lt[r][j] - newm); lt[r][j] = pv; ssum += pv; }
            srow[r] = srow[r] * f + ssum;
            mrow[r] = newm; frow[r] = f;
        }
        __syncthreads();
#pragma unroll
        for (int r = 0; r < 16; ++r) {
            float a = ctx[r] * frow[r];
#pragma unroll
            for (int j = 0; j < 16; ++j) a = fmaf(lt[r][j], vs[j][tid], a);
            ctx[r] = a;
        }
        __syncthreads();
    }
    // write ctx (bf16) into q slot
    for (int r = 0; r < nq; ++r) {
        qkvb[((size_t)g * ml + q0 + r) * Q3 + tid] = f2bf(ctx[r] / srow[r]);
    }
}

// ---------------- K6: out-projection bf16 MFMA + atomic scatter ----------------
__global__ __launch_bounds__(256) void k_out_mfma(const ushort* __restrict__ qkvb,
                                                  const ushort* __restrict__ WfT,
                                                  const float* __restrict__ bff,
                                                  const int* __restrict__ mlp,
                                                  const int* __restrict__ seq,
                                                  float* __restrict__ out) {
    int ml = *mlp;
    int g = blockIdx.z, e = g >> 2, b = g & 3;
    int k0 = blockIdx.y * 128; if (k0 >= ml) return;
    int c0 = blockIdx.x * 128;
    int tid = threadIdx.x;
    __shared__ short As[128 * 64];
    __shared__ short Bs[128 * 64];
    __shared__ int sid_s[128];
    if (tid < 128) sid_s[tid] = (k0 + tid < ml) ? seq[g * SS + k0 + tid] : -1;

    int r = tid >> 1, half = tid & 1;
    int gr = min(k0 + r, ml - 1);
    const ushort* aSrc = qkvb + ((size_t)g * ml + gr) * Q3 + half * 32;
    const ushort* bSrc = WfT + ((size_t)(e * DM + c0 + r)) * HDIM + half * 32;
    char* aw = (char*)As + (size_t)r * 128;
    char* bw = (char*)Bs + (size_t)r * 128;
    int wbase = half * 64;
    int xo = (r & 7) << 4;

    int w = tid >> 6, l = tid & 63;
    int wr = w >> 1, wc = w & 1, lr = l & 15, kb = l >> 4;
    floatx4 acc[4][4] = {};

    int aoff[4][2], boff[4][2];
#pragma unroll
    for (int m = 0; m < 4; ++m) {
        int row = wr * 64 + m * 16 + lr;
#pragma unroll
        for (int s = 0; s < 2; ++s) aoff[m][s] = (row * 128 + s * 64 + kb * 16) ^ ((row & 7) << 4);
    }
#pragma unroll
    for (int n = 0; n < 4; ++n) {
        int row = wc * 64 + n * 16 + lr;
#pragma unroll
        for (int s = 0; s < 2; ++s) boff[n][s] = (row * 128 + s * 64 + kb * 16) ^ ((row & 7) << 4);
    }

    for (int dt = 0; dt < HDIM; dt += 64) {
#pragma unroll
        for (int i = 0; i < 4; ++i) {
            short8 va = *(const short8*)(aSrc + dt + i * 8);
            short8 vb = *(const short8*)(bSrc + dt + i * 8);
            *(short8*)(aw + ((wbase + i * 16) ^ xo)) = va;
            *(short8*)(bw + ((wbase + i * 16) ^ xo)) = vb;
        }
        __syncthreads();
        bf16x8 af[4][2], bfv[4][2];
#pragma unroll
        for (int m = 0; m < 4; ++m) {
            af[m][0] = *(const bf16x8*)((char*)As + aoff[m][0]);
            af[m][1] = *(const bf16x8*)((char*)As + aoff[m][1]);
        }
#pragma unroll
        for (int n = 0; n < 4; ++n) {
            bfv[n][0] = *(const bf16x8*)((char*)Bs + boff[n][0]);
            bfv[n][1] = *(const bf16x8*)((char*)Bs + boff[n][1]);
        }
#pragma unroll
        for (int m = 0; m < 4; ++m)
#pragma unroll
            for (int n = 0; n < 4; ++n) {
                acc[m][n] = __builtin_amdgcn_mfma_f32_16x16x32_bf16(af[m][0], bfv[n][0], acc[m][n], 0, 0, 0);
                acc[m][n] = __builtin_amdgcn_mfma_f32_16x16x32_bf16(af[m][1], bfv[n][1], acc[m][n], 0, 0, 0);
            }
        __syncthreads();
    }
#pragma unroll
    for (int n = 0; n < 4; ++n) {
        int col = c0 + wc * 64 + n * 16 + lr;
        float bias = bff[col];
#pragma unroll
        for (int m = 0; m < 4; ++m) {
            int lrow = wr * 64 + m * 16 + kb * 4;
#pragma unroll
            for (int j = 0; j < 4; ++j) {
                int sid2 = sid_s[lrow + j];
                if (sid2 >= 0) atomicAdd(&out[((size_t)b * SS + sid2) * DM + col], acc[m][n][j] + bias);
            }
        }
    }
}

// ---------------- launch ----------------
extern "C" void kernel_launch(void* const* d_in, const int* in_sizes, int n_in,
                              void* d_out, int out_size, void* d_ws, size_t ws_size,
                              hipStream_t stream) {
    const float* X    = (const float*)d_in[0];
    const float* mask = (const float*)d_in[1];
    const float* wg   = (const float*)d_in[2];
    const float* bg   = (const float*)d_in[3];
    const float* Wqkv = (const float*)d_in[4];
    const float* bqkv = (const float*)d_in[5];
    const float* Wff  = (const float*)d_in[6];
    const float* bff  = (const float*)d_in[7];
    float* out = (float*)d_out;
    char* ws = (char*)d_ws;
    int* counts = (int*)(ws + WSO_COUNTS);
    int* mlp    = (int*)(ws + WSO_ML);
    int* P      = (int*)(ws + WSO_P);
    int* sel    = (int*)(ws + WSO_SEL);
    int* seq    = (int*)(ws + WSO_SEQ);
    ushort* Xb  = (ushort*)(ws + WSO_XB);
    ushort* WqT = (ushort*)(ws + WSO_WQT);
    ushort* WfT = (ushort*)(ws + WSO_WFT);
    ushort* qkvb = (ushort*)(ws + WSO_QKV);

    hipMemsetAsync(ws, 0, 512, stream);
    hipMemsetAsync(d_out, 0, (size_t)out_size * sizeof(float), stream);

    k_gate<<<BB * SS, 64, 0, stream>>>(X, wg, bg, sel, counts);
    k_maxlen<<<1, 64, 0, stream>>>(counts, mlp, P);
    k_seq<<<NG, 256, 0, stream>>>(sel, P, seq);
    k_cvtX<<<8192, 256, 0, stream>>>(X, Xb);
    k_cvtWT<<<dim3(12, 32, NE), 256, 0, stream>>>(Wqkv, WqT, DM, Q3);
    k_cvtWT<<<dim3(32, 4, NE), 256, 0, stream>>>(Wff, WfT, HDIM, DM);
    k_qkv_mfma<<<dim3(6, 16, NG), 256, 0, stream>>>(Xb, WqT, bqkv, mlp, seq, qkvb);
    k_rope<<<dim3(SS, NG), 128, 0, stream>>>(mlp, qkvb);
    k_attn<<<dim3(128, NG), 256, 0, stream>>>(mlp, seq, mask, qkvb);
    k_out_mfma<<<dim3(16, 16, NG), 256, 0, stream>>>(qkvb, WfT, bff, mlp, seq, out);
}

// Round 3
// 1127.303 us; speedup vs baseline: 2.8102x; 1.3582x over previous
//
#include <hip/hip_runtime.h>
#include <math.h>

// Problem constants
#define BB    4
#define SS    2048
#define DM    2048
#define NE    8
#define HDIM  256
#define NOPE_ 128
#define Q3    768
#define NG    32
#define SCALE_ 0.0625f

typedef __attribute__((ext_vector_type(8))) short short8;
typedef __attribute__((ext_vector_type(8))) __bf16 bf16x8;
typedef __attribute__((ext_vector_type(4))) float floatx4;

// ws byte offsets
#define WSO_COUNTS 0
#define WSO_ML     128
#define WSO_P      192
#define WSO_SEL    512
#define WSO_SEQ    40960
#define WSO_XB     0x100000ull    // Xb bf16: 32 MB
#define WSO_WQT    0x2200000ull   // WqkvT bf16 [e][768][2048]: 24 MB
#define WSO_WFT    0x3A00000ull   // WffT bf16 [e][2048][256]: 8 MB
#define WSO_QKV    0x4200000ull   // qkv bf16 [g][ml][768], runtime ml

__device__ __forceinline__ float bf2f(ushort u) {
    union { unsigned i; float f; } v; v.i = ((unsigned)u) << 16; return v.f;
}
__device__ __forceinline__ ushort f2bf(float f) {
    union { float f; unsigned i; } v; v.f = f;
    unsigned u = v.i;
    return (ushort)((u + 0x7FFFu + ((u >> 16) & 1u)) >> 16);
}

// ---------------- K1: gating logits + top2 selection (exact f32) ----------------
__global__ __launch_bounds__(64) void k_gate(const float* __restrict__ X,
                                             const float* __restrict__ wg,
                                             const float* __restrict__ bg,
                                             int* __restrict__ sel,
                                             int* __restrict__ counts) {
    int row = blockIdx.x;
    int lane = threadIdx.x;
    const float* xr = X + (size_t)row * DM;
    float acc[NE];
#pragma unroll
    for (int e = 0; e < NE; ++e) acc[e] = 0.f;
    for (int d = lane; d < DM; d += 64) {
        float x = xr[d];
        const float* w = wg + (size_t)d * NE;
#pragma unroll
        for (int e = 0; e < NE; ++e) acc[e] += x * w[e];
    }
#pragma unroll
    for (int e = 0; e < NE; ++e) {
#pragma unroll
        for (int off = 32; off; off >>= 1) acc[e] += __shfl_xor(acc[e], off);
    }
    if (lane == 0) {
        float lg[NE];
#pragma unroll
        for (int e = 0; e < NE; ++e) lg[e] = acc[e] + bg[e];
        int e1 = 0; float v1 = lg[0];
        for (int e = 1; e < NE; ++e) if (lg[e] > v1) { v1 = lg[e]; e1 = e; }
        int e2 = -1; float v2 = -3.4e38f;
        for (int e = 0; e < NE; ++e) { if (e == e1) continue; if (lg[e] > v2) { v2 = lg[e]; e2 = e; } }
        int b = row / SS;
        sel[row] = (1 << e1) | (1 << e2);
        atomicAdd(&counts[e1 * BB + b], 1);
        atomicAdd(&counts[e2 * BB + b], 1);
    }
}

// ---------------- K2: max_len + padding counts ----------------
__global__ __launch_bounds__(64) void k_maxlen(const int* __restrict__ counts,
                                               int* __restrict__ mlp, int* __restrict__ P) {
    __shared__ int red[64];
    int t = threadIdx.x;
    int c = (t < NG) ? counts[t] : 0;
    red[t] = c; __syncthreads();
    for (int off = 32; off; off >>= 1) { if (t < off) red[t] = max(red[t], red[t + off]); __syncthreads(); }
    int ml = red[0];
    if (t == 0) *mlp = ml;
    if (t < NG) P[t] = ml - c;
}

// ---------------- K3: build seq_ids ----------------
__device__ __forceinline__ int scan256(int v, int tid, int* tmp, int& total) {
    tmp[tid] = v; __syncthreads();
#pragma unroll
    for (int off = 1; off < 256; off <<= 1) {
        int t = (tid >= off) ? tmp[tid - off] : 0;
        __syncthreads();
        tmp[tid] += t;
        __syncthreads();
    }
    total = tmp[255];
    int incl = tmp[tid];
    __syncthreads();
    return incl - v;
}

__global__ __launch_bounds__(256) void k_seq(const int* __restrict__ sel,
                                             const int* __restrict__ P,
                                             int* __restrict__ seq) {
    __shared__ int tmp[256];
    __shared__ int bases[2];
    int g = blockIdx.x; int e = g >> 2, b = g & 3;
    int p = P[g];
    int tid = threadIdx.x;
    if (tid == 0) { bases[0] = 0; bases[1] = 0; }
    __syncthreads();
    for (int c = 0; c < SS; c += 256) {
        int s = c + tid;
        int sb = (sel[b * SS + s] >> e) & 1;
        int un = 1 - sb;
        int tot;
        int exc = scan256(un, tid, tmp, tot);
        int rank_un = bases[0] + exc;
        int take = sb | (un & ((rank_un < p) ? 1 : 0));
        int tot2;
        int exc2 = scan256(take, tid, tmp, tot2);
        int pos = bases[1] + exc2;
        if (take) seq[g * SS + pos] = s;
        __syncthreads();
        if (tid == 0) { bases[0] += tot; bases[1] += tot2; }
        __syncthreads();
    }
}

// ---------------- prep: X -> bf16 ----------------
__global__ __launch_bounds__(256) void k_cvtX(const float* __restrict__ X, ushort* __restrict__ Xb) {
    size_t i = ((size_t)blockIdx.x * 256 + threadIdx.x) * 8;
    float4 f0 = *(const float4*)&X[i];
    float4 f1 = *(const float4*)&X[i + 4];
    short8 o;
    o[0] = (short)f2bf(f0.x); o[1] = (short)f2bf(f0.y); o[2] = (short)f2bf(f0.z); o[3] = (short)f2bf(f0.w);
    o[4] = (short)f2bf(f1.x); o[5] = (short)f2bf(f1.y); o[6] = (short)f2bf(f1.z); o[7] = (short)f2bf(f1.w);
    *(short8*)&Xb[i] = o;
}

// ---------------- prep: W [e][K][N] f32 -> Wt [e][N][K] bf16 ----------------
__global__ __launch_bounds__(256) void k_cvtWT(const float* __restrict__ src, ushort* __restrict__ dst,
                                               int K, int N) {
    __shared__ float tile[64][65];
    int e = blockIdx.z;
    int n0 = blockIdx.x * 64, k0 = blockIdx.y * 64;
    int tid = threadIdx.x;
    for (int i = tid; i < 4096; i += 256) {
        int rr = i >> 6, cc = i & 63;
        tile[rr][cc] = src[((size_t)e * K + k0 + rr) * N + n0 + cc];
    }
    __syncthreads();
    for (int i = tid; i < 4096; i += 256) {
        int rr = i >> 6, cc = i & 63;
        dst[((size_t)e * N + n0 + rr) * K + k0 + cc] = f2bf(tile[cc][rr]);
    }
}

// ---------------- K4: QKV GEMM, bf16 MFMA 128x128xBK64 ----------------
__global__ __launch_bounds__(256) void k_qkv_mfma(const ushort* __restrict__ Xb,
                                                  const ushort* __restrict__ WqT,
                                                  const float* __restrict__ bqkv,
                                                  const int* __restrict__ mlp,
                                                  const int* __restrict__ seq,
                                                  ushort* __restrict__ qkvb) {
    int ml = *mlp;
    int g = blockIdx.z, e = g >> 2, b = g & 3;
    int k0 = blockIdx.y * 128; if (k0 >= ml) return;
    int c0 = blockIdx.x * 128;
    int tid = threadIdx.x;
    __shared__ short As[128 * 64];
    __shared__ short Bs[128 * 64];

    int r = tid >> 1, half = tid & 1;
    int gr = k0 + r;
    int sid = (gr < ml) ? seq[g * SS + gr] : 0;
    const ushort* aSrc = Xb + ((size_t)b * SS + sid) * DM + half * 32;
    const ushort* bSrc = WqT + ((size_t)(e * Q3 + c0 + r)) * DM + half * 32;
    char* aw = (char*)As + (size_t)r * 128;
    char* bw = (char*)Bs + (size_t)r * 128;
    int wbase = half * 64;
    int xo = (r & 7) << 4;

    int w = tid >> 6, l = tid & 63;
    int wr = w >> 1, wc = w & 1, lr = l & 15, kb = l >> 4;
    floatx4 acc[4][4] = {};

    int aoff[4][2], boff[4][2];
#pragma unroll
    for (int m = 0; m < 4; ++m) {
        int row = wr * 64 + m * 16 + lr;
#pragma unroll
        for (int s = 0; s < 2; ++s) aoff[m][s] = (row * 128 + s * 64 + kb * 16) ^ ((row & 7) << 4);
    }
#pragma unroll
    for (int n = 0; n < 4; ++n) {
        int row = wc * 64 + n * 16 + lr;
#pragma unroll
        for (int s = 0; s < 2; ++s) boff[n][s] = (row * 128 + s * 64 + kb * 16) ^ ((row & 7) << 4);
    }

    for (int dt = 0; dt < DM; dt += 64) {
#pragma unroll
        for (int i = 0; i < 4; ++i) {
            short8 va = *(const short8*)(aSrc + dt + i * 8);
            short8 vb = *(const short8*)(bSrc + dt + i * 8);
            *(short8*)(aw + ((wbase + i * 16) ^ xo)) = va;
            *(short8*)(bw + ((wbase + i * 16) ^ xo)) = vb;
        }
        __syncthreads();
        bf16x8 af[4][2], bfv[4][2];
#pragma unroll
        for (int m = 0; m < 4; ++m) {
            af[m][0] = *(const bf16x8*)((char*)As + aoff[m][0]);
            af[m][1] = *(const bf16x8*)((char*)As + aoff[m][1]);
        }
#pragma unroll
        for (int n = 0; n < 4; ++n) {
            bfv[n][0] = *(const bf16x8*)((char*)Bs + boff[n][0]);
            bfv[n][1] = *(const bf16x8*)((char*)Bs + boff[n][1]);
        }
#pragma unroll
        for (int m = 0; m < 4; ++m)
#pragma unroll
            for (int n = 0; n < 4; ++n) {
                acc[m][n] = __builtin_amdgcn_mfma_f32_16x16x32_bf16(af[m][0], bfv[n][0], acc[m][n], 0, 0, 0);
                acc[m][n] = __builtin_amdgcn_mfma_f32_16x16x32_bf16(af[m][1], bfv[n][1], acc[m][n], 0, 0, 0);
            }
        __syncthreads();
    }
#pragma unroll
    for (int n = 0; n < 4; ++n) {
        int col = c0 + wc * 64 + n * 16 + lr;
        float bias = bqkv[e * Q3 + col];
#pragma unroll
        for (int m = 0; m < 4; ++m) {
            int rb = k0 + wr * 64 + m * 16 + kb * 4;
#pragma unroll
            for (int j = 0; j < 4; ++j) {
                int grow = rb + j;
                if (grow < ml) qkvb[((size_t)g * ml + grow) * Q3 + col] = f2bf(acc[m][n][j] + bias);
            }
        }
    }
}

// ---------------- K5: MFMA flash attention (rope folded in) ----------------
// Per block: 64 q rows (4 waves x 16), KV tiles of 32, head dim 256.
__global__ __launch_bounds__(256) void k_attn_mfma(const int* __restrict__ mlp,
                                                   const int* __restrict__ seq,
                                                   const float* __restrict__ mask,
                                                   ushort* __restrict__ qkvb) {
    int ml = *mlp;
    int g = blockIdx.y; int e = g >> 2, b = g & 3;
    int q0 = blockIdx.x * 64;
    if (q0 >= ml) return;

    __shared__ __align__(16) char smem[42496];
    short* Ks = (short*)smem;                 // [32][264] bf16  (K rows, d cols)
    short* Vt = (short*)(smem + 16896);       // [256][40] bf16  (V transposed: [d][k])
    int tid = threadIdx.x;
    int w = tid >> 6, l = tid & 63, lr = l & 15, lg = l >> 4;
    short* Ps = (short*)(smem + 37376) + w * 640;   // per-wave P: [16][40]

    // ---- Q fragments (A-layout: row = lr, k-chunk = lg*8) + RoPE on d in [128,256) ----
    int qrow = q0 + w * 16 + lr;
    int qrc = min(qrow, ml - 1);
    const ushort* qp = qkvb + ((size_t)g * ml + qrc) * Q3;
    bf16x8 qa[8];
#pragma unroll
    for (int s = 0; s < 8; ++s) {
        union { short8 s8; bf16x8 bf; } uu;
        uu.s8 = *(const short8*)(qp + s * 32 + lg * 8);
        if (s >= 4) {
            int d0 = s * 32 + lg * 8;
#pragma unroll
            for (int u = 0; u < 4; ++u) {
                int p = ((d0 - 128) >> 1) + u;
                float xexp = (float)(e * 64 + p) * (1.0f / 512.0f);
                float freq = 1.0f / powf(10000.0f, xexp);
                float ang = (float)qrc * freq;
                float c = cosf(ang), sn = sinf(ang);
                float a = bf2f((ushort)uu.s8[2 * u]), bb = bf2f((ushort)uu.s8[2 * u + 1]);
                uu.s8[2 * u]     = (short)f2bf(a * c - bb * sn);
                uu.s8[2 * u + 1] = (short)f2bf(a * sn + bb * c);
            }
        }
        qa[s] = uu.bf;
    }

    floatx4 acc_o[16] = {};
    float mrun[4], lrun[4];
#pragma unroll
    for (int j = 0; j < 4; ++j) { mrun[j] = -1e30f; lrun[j] = 0.f; }

    // staging decomposition
    int kr = tid >> 3, dc = (tid & 7) * 32;       // K: row kr, d-chunk dc (32 d)
    int vk = tid & 31, vd0 = (tid >> 5) * 32;     // V: col k=vk, d-chunk vd0 (32 d)

    for (int j0 = 0; j0 < ml; j0 += 32) {
        // mask values for this KV tile (issued early, hidden under staging)
        float mv[2]; int valid[2];
#pragma unroll
        for (int t = 0; t < 2; ++t) {
            int kk = j0 + t * 16 + lr;
            valid[t] = (kk < ml);
            int sidk = valid[t] ? seq[g * SS + kk] : 0;
            mv[t] = mask[b * SS + sidk];
        }
        __syncthreads();   // previous iteration's readers done

        // ---- stage K tile [32][264] with RoPE on d in [128,256) ----
        {
            int krow = min(j0 + kr, ml - 1);
            const ushort* kp = qkvb + ((size_t)g * ml + krow) * Q3 + HDIM;
#pragma unroll
            for (int i = 0; i < 4; ++i) {
                int d0 = dc + i * 8;
                short8 v = *(const short8*)(kp + d0);
                if (d0 >= 128) {
#pragma unroll
                    for (int u = 0; u < 4; ++u) {
                        int p = ((d0 - 128) >> 1) + u;
                        float xexp = (float)(e * 64 + p) * (1.0f / 512.0f);
                        float freq = 1.0f / powf(10000.0f, xexp);
                        float ang = (float)krow * freq;
                        float c = cosf(ang), sn = sinf(ang);
                        float a = bf2f((ushort)v[2 * u]), bb = bf2f((ushort)v[2 * u + 1]);
                        v[2 * u]     = (short)f2bf(a * c - bb * sn);
                        v[2 * u + 1] = (short)f2bf(a * sn + bb * c);
                    }
                }
                *(short8*)(Ks + kr * 264 + d0) = v;
            }
        }
        // ---- stage V^T [256][40] ----
        {
            int vrow = min(j0 + vk, ml - 1);
            const ushort* vp = qkvb + ((size_t)g * ml + vrow) * Q3 + 2 * HDIM;
#pragma unroll
            for (int i = 0; i < 4; ++i) {
                short8 v = *(const short8*)(vp + vd0 + i * 8);
#pragma unroll
                for (int u = 0; u < 8; ++u)
                    Vt[(vd0 + i * 8 + u) * 40 + vk] = v[u];
            }
        }
        __syncthreads();

        // ---- QK^T: S[16q x 32k] per wave ----
        floatx4 s0 = {}, s1 = {};
#pragma unroll
        for (int s = 0; s < 8; ++s) {
            bf16x8 kb0 = *(const bf16x8*)(Ks + lr * 264 + s * 32 + lg * 8);
            bf16x8 kb1 = *(const bf16x8*)(Ks + (16 + lr) * 264 + s * 32 + lg * 8);
            s0 = __builtin_amdgcn_mfma_f32_16x16x32_bf16(qa[s], kb0, s0, 0, 0, 0);
            s1 = __builtin_amdgcn_mfma_f32_16x16x32_bf16(qa[s], kb1, s1, 0, 0, 0);
        }

        // ---- wave-parallel online softmax (C-layout: col=lr, row=lg*4+j) ----
        float sv[2][4], pb[2][4];
#pragma unroll
        for (int j = 0; j < 4; ++j) {
            sv[0][j] = valid[0] ? (s0[j] * SCALE_ - 1e6f * (1.f - mv[0])) : -1e30f;
            sv[1][j] = valid[1] ? (s1[j] * SCALE_ - 1e6f * (1.f - mv[1])) : -1e30f;
        }
        float rmax[4];
#pragma unroll
        for (int j = 0; j < 4; ++j) rmax[j] = fmaxf(sv[0][j], sv[1][j]);
#pragma unroll
        for (int off = 1; off < 16; off <<= 1) {
#pragma unroll
            for (int j = 0; j < 4; ++j) rmax[j] = fmaxf(rmax[j], __shfl_xor(rmax[j], off));
        }
        float fscale[4];
#pragma unroll
        for (int j = 0; j < 4; ++j) {
            float mnew = fmaxf(mrun[j], rmax[j]);
            fscale[j] = __expf(mrun[j] - mnew);
            mrun[j] = mnew;
        }
        float psum[4];
#pragma unroll
        for (int j = 0; j < 4; ++j) {
            pb[0][j] = __expf(sv[0][j] - mrun[j]);
            pb[1][j] = __expf(sv[1][j] - mrun[j]);
            psum[j] = pb[0][j] + pb[1][j];
        }
#pragma unroll
        for (int off = 1; off < 16; off <<= 1) {
#pragma unroll
            for (int j = 0; j < 4; ++j) psum[j] += __shfl_xor(psum[j], off);
        }
#pragma unroll
        for (int j = 0; j < 4; ++j) lrun[j] = lrun[j] * fscale[j] + psum[j];
        // rescale O accumulator
#pragma unroll
        for (int n = 0; n < 16; ++n) {
#pragma unroll
            for (int j = 0; j < 4; ++j) acc_o[n][j] *= fscale[j];
        }

        // ---- P (C-layout) -> A-layout via per-wave LDS (no barrier needed) ----
#pragma unroll
        for (int t = 0; t < 2; ++t)
#pragma unroll
            for (int j = 0; j < 4; ++j)
                Ps[(lg * 4 + j) * 40 + t * 16 + lr] = (short)f2bf(pb[t][j]);
        bf16x8 pa = *(const bf16x8*)(Ps + lr * 40 + lg * 8);

        // ---- PV: O[16q x 256d] += P x V ----
#pragma unroll
        for (int n = 0; n < 16; ++n) {
            bf16x8 vb = *(const bf16x8*)(Vt + (n * 16 + lr) * 40 + lg * 8);
            acc_o[n] = __builtin_amdgcn_mfma_f32_16x16x32_bf16(pa, vb, acc_o[n], 0, 0, 0);
        }
    }

    // ---- epilogue: normalize, stage to LDS, coalesced store into q-slot ----
    __syncthreads();
    short* Ol = (short*)smem;   // [64][264]
    float rinv[4];
#pragma unroll
    for (int j = 0; j < 4; ++j) rinv[j] = 1.0f / lrun[j];
#pragma unroll
    for (int n = 0; n < 16; ++n)
#pragma unroll
        for (int j = 0; j < 4; ++j)
            Ol[(w * 16 + lg * 4 + j) * 264 + n * 16 + lr] = (short)f2bf(acc_o[n][j] * rinv[j]);
    __syncthreads();
    for (int idx = tid; idx < 64 * 32; idx += 256) {
        int r = idx >> 5, ch = idx & 31;
        int qr = q0 + r;
        if (qr < ml) {
            short8 v = *(const short8*)(Ol + r * 264 + ch * 8);
            *(short8*)(qkvb + ((size_t)g * ml + qr) * Q3 + ch * 8) = v;
        }
    }
}

// ---------------- K6: out-projection bf16 MFMA + atomic scatter ----------------
__global__ __launch_bounds__(256) void k_out_mfma(const ushort* __restrict__ qkvb,
                                                  const ushort* __restrict__ WfT,
                                                  const float* __restrict__ bff,
                                                  const int* __restrict__ mlp,
                                                  const int* __restrict__ seq,
                                                  float* __restrict__ out) {
    int ml = *mlp;
    int g = blockIdx.z, e = g >> 2, b = g & 3;
    int k0 = blockIdx.y * 128; if (k0 >= ml) return;
    int c0 = blockIdx.x * 128;
    int tid = threadIdx.x;
    __shared__ short As[128 * 64];
    __shared__ short Bs[128 * 64];
    __shared__ int sid_s[128];
    if (tid < 128) sid_s[tid] = (k0 + tid < ml) ? seq[g * SS + k0 + tid] : -1;

    int r = tid >> 1, half = tid & 1;
    int gr = min(k0 + r, ml - 1);
    const ushort* aSrc = qkvb + ((size_t)g * ml + gr) * Q3 + half * 32;
    const ushort* bSrc = WfT + ((size_t)(e * DM + c0 + r)) * HDIM + half * 32;
    char* aw = (char*)As + (size_t)r * 128;
    char* bw = (char*)Bs + (size_t)r * 128;
    int wbase = half * 64;
    int xo = (r & 7) << 4;

    int w = tid >> 6, l = tid & 63;
    int wr = w >> 1, wc = w & 1, lr = l & 15, kb = l >> 4;
    floatx4 acc[4][4] = {};

    int aoff[4][2], boff[4][2];
#pragma unroll
    for (int m = 0; m < 4; ++m) {
        int row = wr * 64 + m * 16 + lr;
#pragma unroll
        for (int s = 0; s < 2; ++s) aoff[m][s] = (row * 128 + s * 64 + kb * 16) ^ ((row & 7) << 4);
    }
#pragma unroll
    for (int n = 0; n < 4; ++n) {
        int row = wc * 64 + n * 16 + lr;
#pragma unroll
        for (int s = 0; s < 2; ++s) boff[n][s] = (row * 128 + s * 64 + kb * 16) ^ ((row & 7) << 4);
    }

    for (int dt = 0; dt < HDIM; dt += 64) {
#pragma unroll
        for (int i = 0; i < 4; ++i) {
            short8 va = *(const short8*)(aSrc + dt + i * 8);
            short8 vb = *(const short8*)(bSrc + dt + i * 8);
            *(short8*)(aw + ((wbase + i * 16) ^ xo)) = va;
            *(short8*)(bw + ((wbase + i * 16) ^ xo)) = vb;
        }
        __syncthreads();
        bf16x8 af[4][2], bfv[4][2];
#pragma unroll
        for (int m = 0; m < 4; ++m) {
            af[m][0] = *(const bf16x8*)((char*)As + aoff[m][0]);
            af[m][1] = *(const bf16x8*)((char*)As + aoff[m][1]);
        }
#pragma unroll
        for (int n = 0; n < 4; ++n) {
            bfv[n][0] = *(const bf16x8*)((char*)Bs + boff[n][0]);
            bfv[n][1] = *(const bf16x8*)((char*)Bs + boff[n][1]);
        }
#pragma unroll
        for (int m = 0; m < 4; ++m)
#pragma unroll
            for (int n = 0; n < 4; ++n) {
                acc[m][n] = __builtin_amdgcn_mfma_f32_16x16x32_bf16(af[m][0], bfv[n][0], acc[m][n], 0, 0, 0);
                acc[m][n] = __builtin_amdgcn_mfma_f32_16x16x32_bf16(af[m][1], bfv[n][1], acc[m][n], 0, 0, 0);
            }
        __syncthreads();
    }
#pragma unroll
    for (int n = 0; n < 4; ++n) {
        int col = c0 + wc * 64 + n * 16 + lr;
        float bias = bff[col];
#pragma unroll
        for (int m = 0; m < 4; ++m) {
            int lrow = wr * 64 + m * 16 + kb * 4;
#pragma unroll
            for (int j = 0; j < 4; ++j) {
                int sid2 = sid_s[lrow + j];
                if (sid2 >= 0) atomicAdd(&out[((size_t)b * SS + sid2) * DM + col], acc[m][n][j] + bias);
            }
        }
    }
}

// ---------------- launch ----------------
extern "C" void kernel_launch(void* const* d_in, const int* in_sizes, int n_in,
                              void* d_out, int out_size, void* d_ws, size_t ws_size,
                              hipStream_t stream) {
    const float* X    = (const float*)d_in[0];
    const float* mask = (const float*)d_in[1];
    const float* wg   = (const float*)d_in[2];
    const float* bg   = (const float*)d_in[3];
    const float* Wqkv = (const float*)d_in[4];
    const float* bqkv = (const float*)d_in[5];
    const float* Wff  = (const float*)d_in[6];
    const float* bff  = (const float*)d_in[7];
    float* out = (float*)d_out;
    char* ws = (char*)d_ws;
    int* counts = (int*)(ws + WSO_COUNTS);
    int* mlp    = (int*)(ws + WSO_ML);
    int* P      = (int*)(ws + WSO_P);
    int* sel    = (int*)(ws + WSO_SEL);
    int* seq    = (int*)(ws + WSO_SEQ);
    ushort* Xb  = (ushort*)(ws + WSO_XB);
    ushort* WqT = (ushort*)(ws + WSO_WQT);
    ushort* WfT = (ushort*)(ws + WSO_WFT);
    ushort* qkvb = (ushort*)(ws + WSO_QKV);

    hipMemsetAsync(ws, 0, 512, stream);
    hipMemsetAsync(d_out, 0, (size_t)out_size * sizeof(float), stream);

    k_gate<<<BB * SS, 64, 0, stream>>>(X, wg, bg, sel, counts);
    k_maxlen<<<1, 64, 0, stream>>>(counts, mlp, P);
    k_seq<<<NG, 256, 0, stream>>>(sel, P, seq);
    k_cvtX<<<8192, 256, 0, stream>>>(X, Xb);
    k_cvtWT<<<dim3(12, 32, NE), 256, 0, stream>>>(Wqkv, WqT, DM, Q3);
    k_cvtWT<<<dim3(32, 4, NE), 256, 0, stream>>>(Wff, WfT, HDIM, DM);
    k_qkv_mfma<<<dim3(6, 16, NG), 256, 0, stream>>>(Xb, WqT, bqkv, mlp, seq, qkvb);
    k_attn_mfma<<<dim3(32, NG), 256, 0, stream>>>(mlp, seq, mask, qkvb);
    k_out_mfma<<<dim3(16, 16, NG), 256, 0, stream>>>(qkvb, WfT, bff, mlp, seq, out);
}